// Round 3
// baseline (546.779 us; speedup 1.0000x reference)
//
#include <hip/hip_runtime.h>
#include <math.h>
#include <float.h>

#define D 256
#define K 1024
#define NROWS 32768
#define RPB 16          // rows per block
#define KPASS 256       // codes per pass
#define NPASS 4         // K / KPASS
#define DT 16           // d-chunk per codebook LDS tile
#define NDT 16          // D / DT
#define XSTRIDE 264     // 256 + 8 pad, keeps 16B alignment per row
#define CSTRIDE 20      // 16 + 4 pad, 16B-aligned rows, conflict-free reads
#define MARGIN 0.75f    // z-margin for np-replica near-tie refinement

#define LOSS_OFF 8388608
#define IDX_OFF  8388609

// ---- numpy pairwise sum replica for sum(a*a) over 128 contiguous floats ----
// numpy: 8 accumulators unrolled, combined ((r0+r1)+(r2+r3))+((r4+r5)+(r6+r7)).
// __fmul_rn/__fadd_rn block FMA contraction (numpy rounds a*a, then adds).
__device__ __forceinline__ float np_sq_block128(const float* a) {
    float r0 = __fmul_rn(a[0], a[0]);
    float r1 = __fmul_rn(a[1], a[1]);
    float r2 = __fmul_rn(a[2], a[2]);
    float r3 = __fmul_rn(a[3], a[3]);
    float r4 = __fmul_rn(a[4], a[4]);
    float r5 = __fmul_rn(a[5], a[5]);
    float r6 = __fmul_rn(a[6], a[6]);
    float r7 = __fmul_rn(a[7], a[7]);
    for (int i = 8; i < 128; i += 8) {
        r0 = __fadd_rn(r0, __fmul_rn(a[i + 0], a[i + 0]));
        r1 = __fadd_rn(r1, __fmul_rn(a[i + 1], a[i + 1]));
        r2 = __fadd_rn(r2, __fmul_rn(a[i + 2], a[i + 2]));
        r3 = __fadd_rn(r3, __fmul_rn(a[i + 3], a[i + 3]));
        r4 = __fadd_rn(r4, __fmul_rn(a[i + 4], a[i + 4]));
        r5 = __fadd_rn(r5, __fmul_rn(a[i + 5], a[i + 5]));
        r6 = __fadd_rn(r6, __fmul_rn(a[i + 6], a[i + 6]));
        r7 = __fadd_rn(r7, __fmul_rn(a[i + 7], a[i + 7]));
    }
    float tA = __fadd_rn(__fadd_rn(r0, r1), __fadd_rn(r2, r3));
    float tB = __fadd_rn(__fadd_rn(r4, r5), __fadd_rn(r6, r7));
    return __fadd_rn(tA, tB);
}

// ---- codebook squared norms (numpy pairwise replica, n=256 -> 128+128) -----
__global__ void vq_b2(const float* __restrict__ cb, float* __restrict__ b2) {
    int k = blockIdx.x * blockDim.x + threadIdx.x;
    if (k >= K) return;
    const float* c = cb + (size_t)k * D;
    b2[k] = __fadd_rn(np_sq_block128(c), np_sq_block128(c + 128));
}

// ---- fused distance GEMM + argmin + online softmax stats + outputs ----------
__global__ __launch_bounds__(256, 2)
void vq_main(const float* __restrict__ x, const float* __restrict__ cb,
             const float* __restrict__ b2, float* __restrict__ avg_acc,
             float* __restrict__ scal, float* __restrict__ out)
{
    __shared__ __align__(16) float xs[RPB][XSTRIDE];
    __shared__ __align__(16) float cs[KPASS][CSTRIDE];

    const int t = threadIdx.x;
    const int wave = t >> 6;   // wave w owns rows 4w..4w+3 of the block tile
    const int lane = t & 63;   // lane l owns codes {l, l+64, l+128, l+192} per pass
    const int r0 = blockIdx.x * RPB;

    // stage x tile [16][256] once; reused for GEMM d-tiles and epilogue
    {
        const float4* xg = (const float4*)x + (size_t)r0 * (D / 4);
        #pragma unroll
        for (int it = 0; it < 4; ++it) {
            int f = it * 256 + t;              // 0..1023 float4s
            int row = f >> 6, c4 = f & 63;
            float4 v = xg[row * (D / 4) + c4];
            *(float4*)&xs[row][c4 * 4] = v;
        }
    }

    float acc[NPASS][4][4];                    // [pass][row][code] = x·c
    #pragma unroll
    for (int p = 0; p < NPASS; ++p)
        #pragma unroll
        for (int i = 0; i < 4; ++i)
            #pragma unroll
            for (int j = 0; j < 4; ++j)
                acc[p][i][j] = 0.f;

    #pragma unroll
    for (int p = 0; p < NPASS; ++p) {
        for (int dt = 0; dt < NDT; ++dt) {
            __syncthreads();
            {   // stage codebook tile: 256 codes x 16 dims
                const float* cg = cb + (size_t)(p * KPASS) * D + dt * DT;
                #pragma unroll
                for (int l = 0; l < 4; ++l) {
                    int f = l * 256 + t;
                    int code = f >> 2, dd4 = f & 3;
                    float4 v = *(const float4*)(cg + (size_t)code * D + dd4 * 4);
                    *(float4*)&cs[code][dd4 * 4] = v;
                }
            }
            __syncthreads();
            const int rbl = wave * 4;
            #pragma unroll
            for (int dd4 = 0; dd4 < 4; ++dd4) {
                float4 xv[4], cv[4];
                #pragma unroll
                for (int i = 0; i < 4; ++i)   // broadcast reads (free)
                    xv[i] = *(const float4*)&xs[rbl + i][dt * DT + dd4 * 4];
                #pragma unroll
                for (int j = 0; j < 4; ++j)   // stride-20 rows -> conflict-free
                    cv[j] = *(const float4*)&cs[lane + 64 * j][dd4 * 4];
                #pragma unroll
                for (int i = 0; i < 4; ++i)
                    #pragma unroll
                    for (int j = 0; j < 4; ++j)
                        acc[p][i][j] += xv[i].x * cv[j].x + xv[i].y * cv[j].y
                                      + xv[i].z * cv[j].z + xv[i].w * cv[j].w;
            }
        }
    }

    // ---- epilogue: z = -dist/temp + const = 200*dot - 100*||c||^2 ----------
    float b2r[NPASS][4];
    #pragma unroll
    for (int p = 0; p < NPASS; ++p)
        #pragma unroll
        for (int j = 0; j < 4; ++j)
            b2r[p][j] = b2[p * KPASS + j * 64 + lane];

    #pragma unroll
    for (int p = 0; p < NPASS; ++p)
        #pragma unroll
        for (int i = 0; i < 4; ++i)
            #pragma unroll
            for (int j = 0; j < 4; ++j)
                acc[p][i][j] = 200.f * acc[p][i][j] - 100.f * b2r[p][j];

    float wave_mse = 0.f;
    float waveH = 0.f;
    const int rb = wave * 4;

    #pragma unroll
    for (int i = 0; i < 4; ++i) {
        const int row = r0 + wave * 4 + i;
        // local then wave max/argmax (ascending k order -> first-min tiebreak)
        float m = -INFINITY; int bk = K;
        #pragma unroll
        for (int p = 0; p < NPASS; ++p)
            #pragma unroll
            for (int j = 0; j < 4; ++j) {
                float z = acc[p][i][j];
                int k = p * KPASS + j * 64 + lane;
                if (z > m) { m = z; bk = k; }
            }
        #pragma unroll
        for (int off = 32; off > 0; off >>= 1) {
            float om = __shfl_xor(m, off);
            int   ok = __shfl_xor(bk, off);
            if (om > m || (om == m && ok < bk)) { m = om; bk = ok; }
        }

        // ---- near-tie refinement: replicate numpy's fp32 dist pipeline -----
        int cnt = 0; int cand[4];
        #pragma unroll
        for (int p = 0; p < NPASS; ++p)
            #pragma unroll
            for (int j = 0; j < 4; ++j) {
                if (acc[p][i][j] > m - MARGIN) {
                    if (cnt < 4) cand[cnt] = p * KPASS + j * 64 + lane;
                    cnt++;
                }
            }
        int totc = cnt;
        #pragma unroll
        for (int off = 32; off > 0; off >>= 1) totc += __shfl_xor(totc, off);
        if (totc > 1) {     // wave-uniform slow path
            const float* xrow = &xs[rb + i][0];
            // numpy-replica a2 (fp32 pairwise of x*x) — wave-uniform redundant
            float a2f = __fadd_rn(np_sq_block128(xrow), np_sq_block128(xrow + 128));
            unsigned long long bal = __ballot(cnt > 0);
            float bestd = FLT_MAX; int bestk = K;
            while (bal) {
                int src = __ffsll((long long)bal) - 1;
                bal &= bal - 1;
                int scnt = __shfl(cnt, src);
                if (scnt > 4) scnt = 4;
                for (int c = 0; c < scnt; ++c) {
                    int k = __shfl(cand[c], src);
                    // exact dot in fp64 (stand-in for BLAS fp32 sgemm), then
                    // round to fp32 and apply numpy's fp32 combine + rounding.
                    double s = 0.0;
                    #pragma unroll
                    for (int dd = 0; dd < 4; ++dd) {
                        double cx = (double)cb[(size_t)k * D + lane * 4 + dd];
                        double xx = (double)xrow[lane * 4 + dd];
                        s += xx * cx;
                    }
                    #pragma unroll
                    for (int off = 32; off > 0; off >>= 1)
                        s += __shfl_xor(s, off);
                    float abf = (float)s;
                    float t1  = __fadd_rn(a2f, b2[k]);
                    float dnp = __fsub_rn(t1, __fmul_rn(2.0f, abf));
                    if (dnp < bestd || (dnp == bestd && k < bestk)) {
                        bestd = dnp; bestk = k;
                    }
                }
            }
            bk = bestk;
        }

        // S = sum e^{z-m}, T = sum (z-m) e^{z-m}
        float S = 0.f, T = 0.f;
        #pragma unroll
        for (int p = 0; p < NPASS; ++p)
            #pragma unroll
            for (int j = 0; j < 4; ++j) {
                float zz = acc[p][i][j] - m;
                float ee = expf(zz);
                acc[p][i][j] = ee;            // reuse for sparse emit
                S += ee; T += zz * ee;
            }
        #pragma unroll
        for (int off = 32; off > 0; off >>= 1) {
            S += __shfl_xor(S, off);
            T += __shfl_xor(T, off);
        }
        float invS = 1.f / S;
        // avg_probs: ~2 nonzero entries per row survive exp underflow
        #pragma unroll
        for (int p = 0; p < NPASS; ++p)
            #pragma unroll
            for (int j = 0; j < 4; ++j) {
                float pr = acc[p][i][j] * invS;
                if (pr > 1e-12f)
                    atomicAdd(&avg_acc[p * KPASS + j * 64 + lane], pr);
            }
        if (lane == 0) {
            waveH += T * invS - logf(S);       // sum_k p log p for this row
            out[IDX_OFF + row] = (float)bk;    // indices compared as float
        }
        // gather + straight-through forward (x + (q - x), matching ref fp32)
        float4 q  = *(const float4*)(cb + (size_t)bk * D + lane * 4);
        float4 xv = *(const float4*)&xs[rb + i][lane * 4];
        float4 st;
        st.x = xv.x + (q.x - xv.x); st.y = xv.y + (q.y - xv.y);
        st.z = xv.z + (q.z - xv.z); st.w = xv.w + (q.w - xv.w);
        *(float4*)(out + (size_t)row * D + lane * 4) = st;
        float dx = q.x - xv.x, dy = q.y - xv.y, dz = q.z - xv.z, dw = q.w - xv.w;
        wave_mse += dx * dx + dy * dy + dz * dz + dw * dw;
    }

    #pragma unroll
    for (int off = 32; off > 0; off >>= 1)
        wave_mse += __shfl_xor(wave_mse, off);
    if (lane == 0) {
        atomicAdd(&scal[0], wave_mse);
        atomicAdd(&scal[1], waveH);
    }
}

// ---- finalize loss ----------------------------------------------------------
__global__ __launch_bounds__(1024)
void vq_fin(const float* __restrict__ avg_acc, const float* __restrict__ scal,
            float* __restrict__ out)
{
    __shared__ float sred[16];
    int t = threadIdx.x;
    float ap = avg_acc[t] * (1.f / 32768.f);
    float v = ap * logf(ap + 1e-5f);
    #pragma unroll
    for (int off = 32; off > 0; off >>= 1) v += __shfl_xor(v, off);
    if ((t & 63) == 0) sred[t >> 6] = v;
    __syncthreads();
    if (t == 0) {
        float s = 0.f;
        for (int w = 0; w < 16; ++w) s += sred[w];
        float avg_entropy = -s;
        float sampleH = -scal[1] * (1.f / 32768.f);     // sample entropy
        float mse = scal[0] * (1.f / 8388608.f);
        float loss = 1.25f * mse + 0.1f * (sampleH - avg_entropy);
        out[LOSS_OFF] = loss;
    }
}

extern "C" void kernel_launch(void* const* d_in, const int* in_sizes, int n_in,
                              void* d_out, int out_size, void* d_ws, size_t ws_size,
                              hipStream_t stream)
{
    const float* x  = (const float*)d_in[0];
    const float* cb = (const float*)d_in[1];
    float* out = (float*)d_out;
    float* ws  = (float*)d_ws;
    float* b2      = ws;            // [1024]
    float* avg_acc = ws + K;        // [1024]
    float* scal    = ws + 2 * K;    // [2]: mse, sum(p log p)

    hipMemsetAsync(d_ws, 0, (2 * K + 2) * sizeof(float), stream);
    vq_b2<<<K / 256, 256, 0, stream>>>(cb, b2);
    vq_main<<<NROWS / RPB, 256, 0, stream>>>(x, cb, b2, avg_acc, scal, out);
    vq_fin<<<1, 1024, 0, stream>>>(avg_acc, scal, out);
}

// Round 4
// 370.311 us; speedup vs baseline: 1.4765x; 1.4765x over previous
//
#include <hip/hip_runtime.h>
#include <math.h>
#include <float.h>

#define D 256
#define K 1024
#define NROWS 32768
#define MARGIN 1.0f     // z-margin for np-replica near-tie refinement (fp16 fast-z)
#define MAXCAND 12

#define LOSS_OFF 8388608
#define IDX_OFF  8388609

typedef _Float16 h8 __attribute__((ext_vector_type(8)));
typedef _Float16 h4 __attribute__((ext_vector_type(4)));
typedef float    v4f __attribute__((ext_vector_type(4)));

// ---- numpy pairwise sum replica for sum(a*a) over 128 contiguous floats ----
__device__ __forceinline__ float np_sq_block128(const float* a) {
    float r0 = __fmul_rn(a[0], a[0]);
    float r1 = __fmul_rn(a[1], a[1]);
    float r2 = __fmul_rn(a[2], a[2]);
    float r3 = __fmul_rn(a[3], a[3]);
    float r4 = __fmul_rn(a[4], a[4]);
    float r5 = __fmul_rn(a[5], a[5]);
    float r6 = __fmul_rn(a[6], a[6]);
    float r7 = __fmul_rn(a[7], a[7]);
    for (int i = 8; i < 128; i += 8) {
        r0 = __fadd_rn(r0, __fmul_rn(a[i + 0], a[i + 0]));
        r1 = __fadd_rn(r1, __fmul_rn(a[i + 1], a[i + 1]));
        r2 = __fadd_rn(r2, __fmul_rn(a[i + 2], a[i + 2]));
        r3 = __fadd_rn(r3, __fmul_rn(a[i + 3], a[i + 3]));
        r4 = __fadd_rn(r4, __fmul_rn(a[i + 4], a[i + 4]));
        r5 = __fadd_rn(r5, __fmul_rn(a[i + 5], a[i + 5]));
        r6 = __fadd_rn(r6, __fmul_rn(a[i + 6], a[i + 6]));
        r7 = __fadd_rn(r7, __fmul_rn(a[i + 7], a[i + 7]));
    }
    float tA = __fadd_rn(__fadd_rn(r0, r1), __fadd_rn(r2, r3));
    float tB = __fadd_rn(__fadd_rn(r4, r5), __fadd_rn(r6, r7));
    return __fadd_rn(tA, tB);
}

// ---- codebook squared norms (numpy pairwise replica, n=256 -> 128+128) -----
__global__ void vq_b2(const float* __restrict__ cb, float* __restrict__ b2) {
    int k = blockIdx.x * blockDim.x + threadIdx.x;
    if (k >= K) return;
    const float* c = cb + (size_t)k * D;
    b2[k] = __fadd_rn(np_sq_block128(c), np_sq_block128(c + 128));
}

// ---- codebook fp32 -> fp16 --------------------------------------------------
__global__ void vq_cvt(const float* __restrict__ cb, _Float16* __restrict__ c16) {
    int i = blockIdx.x * blockDim.x + threadIdx.x;   // 65536 float4 groups
    float4 v = ((const float4*)cb)[i];
    h4 o = { (_Float16)v.x, (_Float16)v.y, (_Float16)v.z, (_Float16)v.w };
    ((h4*)c16)[i] = o;
}

// ---- fused MFMA distance GEMM + argmin + softmax stats + outputs -----------
// Block: 512 thr = 8 waves = 2 row-groups (16 rows) x 4 code-quarters (256).
// Wave tile: M=16 rows, N=256 codes (16 MFMA N-tiles), K=256 (8 steps of 32).
__global__ __launch_bounds__(512)
void vq_mfma(const float* __restrict__ x, const float* __restrict__ cb,
             const _Float16* __restrict__ c16, const float* __restrict__ b2,
             float* __restrict__ avg_acc, float* __restrict__ scal,
             float* __restrict__ out)
{
    __shared__ float mred[4][32];
    __shared__ int   kred[4][32];
    __shared__ float sred[4][32];
    __shared__ float tred[4][32];
    __shared__ int   bkl[32];
    __shared__ int   candn[32];
    __shared__ int   candk[32][MAXCAND];
    __shared__ __align__(16) float xbuf[256];

    const int t    = threadIdx.x;
    const int w    = t >> 6;          // wave 0..7
    const int ln64 = t & 63;
    const int qd   = ln64 >> 4;       // quad 0..3 (k-chunk for A/B, row-group for C)
    const int ln   = ln64 & 15;       // m (A) / n (B) / col (C)
    const int g    = w >> 2;          // row-group 0..1
    const int q    = w & 3;           // code-quarter 0..3
    const int r0   = blockIdx.x * 32; // block's first row
    const int rw   = r0 + 16 * g;     // wave's first row

    if (t < 32) candn[t] = 0;
    __syncthreads();

    // ---- GEMM: acc[tile][reg]; D-layout: col=ln, row=qd*4+reg ----
    v4f acc[16];
    #pragma unroll
    for (int tt = 0; tt < 16; ++tt) acc[tt] = (v4f)0.f;

    const _Float16* cbase = c16 + ((size_t)(256 * q + ln)) * D + qd * 8;
    const float*    abase = x   + ((size_t)(rw + ln)) * D + qd * 8;

    #pragma unroll
    for (int s = 0; s < 8; ++s) {
        float4 a0 = *(const float4*)(abase + 32 * s);
        float4 a1 = *(const float4*)(abase + 32 * s + 4);
        h8 af;
        af[0] = (_Float16)a0.x; af[1] = (_Float16)a0.y;
        af[2] = (_Float16)a0.z; af[3] = (_Float16)a0.w;
        af[4] = (_Float16)a1.x; af[5] = (_Float16)a1.y;
        af[6] = (_Float16)a1.z; af[7] = (_Float16)a1.w;
        #pragma unroll
        for (int tt = 0; tt < 16; ++tt) {
            h8 bf = *(const h8*)(cbase + (size_t)tt * 16 * D + 32 * s);
            acc[tt] = __builtin_amdgcn_mfma_f32_16x16x32_f16(af, bf, acc[tt], 0, 0, 0);
        }
    }

    // ---- z = 200*dot - 100*||c||^2 ----
    float b2c[16];
    #pragma unroll
    for (int tt = 0; tt < 16; ++tt) b2c[tt] = b2[256 * q + 16 * tt + ln];
    #pragma unroll
    for (int tt = 0; tt < 16; ++tt)
        #pragma unroll
        for (int r = 0; r < 4; ++r)
            acc[tt][r] = 200.f * acc[tt][r] - 100.f * b2c[tt];

    // ---- per-row (row = qd*4+r of wave) local max over 16 cols ----
    float m[4]; int bk[4];
    #pragma unroll
    for (int r = 0; r < 4; ++r) { m[r] = -INFINITY; bk[r] = K; }
    #pragma unroll
    for (int tt = 0; tt < 16; ++tt)
        #pragma unroll
        for (int r = 0; r < 4; ++r) {
            float z = acc[tt][r];
            int code = 256 * q + 16 * tt + ln;
            if (z > m[r]) { m[r] = z; bk[r] = code; }
        }
    #pragma unroll
    for (int off = 1; off < 16; off <<= 1)
        #pragma unroll
        for (int r = 0; r < 4; ++r) {
            float om = __shfl_xor(m[r], off);
            int   ok = __shfl_xor(bk[r], off);
            if (om > m[r] || (om == m[r] && ok < bk[r])) { m[r] = om; bk[r] = ok; }
        }
    if (ln == 0)
        #pragma unroll
        for (int r = 0; r < 4; ++r) {
            int rl = 16 * g + 4 * qd + r;
            mred[q][rl] = m[r]; kred[q][rl] = bk[r];
        }
    __syncthreads();

    // ---- combine quarters (codes ascend with quarter -> '>' keeps low idx) --
    float mf[4]; int kf[4];
    #pragma unroll
    for (int r = 0; r < 4; ++r) {
        int rl = 16 * g + 4 * qd + r;
        mf[r] = mred[0][rl]; kf[r] = kred[0][rl];
        #pragma unroll
        for (int qq = 1; qq < 4; ++qq) {
            float mm = mred[qq][rl];
            if (mm > mf[r]) { mf[r] = mm; kf[r] = kred[qq][rl]; }
        }
    }

    // ---- S,T with global max; candidate append; stash e-values ----
    float S[4] = {0, 0, 0, 0}, T[4] = {0, 0, 0, 0};
    #pragma unroll
    for (int tt = 0; tt < 16; ++tt)
        #pragma unroll
        for (int r = 0; r < 4; ++r) {
            float z  = acc[tt][r];
            float zz = z - mf[r];
            float e  = __expf(zz);
            if (z > mf[r] - MARGIN) {
                int rl = 16 * g + 4 * qd + r;
                int slot = atomicAdd(&candn[rl], 1);
                if (slot < MAXCAND) candk[rl][slot] = 256 * q + 16 * tt + ln;
            }
            S[r] += e; T[r] += zz * e;
            acc[tt][r] = e;
        }
    #pragma unroll
    for (int off = 1; off < 16; off <<= 1)
        #pragma unroll
        for (int r = 0; r < 4; ++r) {
            S[r] += __shfl_xor(S[r], off);
            T[r] += __shfl_xor(T[r], off);
        }
    if (ln == 0)
        #pragma unroll
        for (int r = 0; r < 4; ++r) {
            int rl = 16 * g + 4 * qd + r;
            sred[q][rl] = S[r]; tred[q][rl] = T[r];
        }
    __syncthreads();

    float iS[4];
    #pragma unroll
    for (int r = 0; r < 4; ++r) {
        int rl = 16 * g + 4 * qd + r;
        float Sf = sred[0][rl] + sred[1][rl] + sred[2][rl] + sred[3][rl];
        float Tf = tred[0][rl] + tred[1][rl] + tred[2][rl] + tred[3][rl];
        iS[r] = 1.f / Sf;
        if (q == 0 && ln == 0) {
            bkl[rl] = kf[r];
            atomicAdd(&scal[1], Tf * iS[r] - __logf(Sf));   // sum_k p log p
        }
    }

    // ---- sparse avg_probs emission ----
    #pragma unroll
    for (int tt = 0; tt < 16; ++tt)
        #pragma unroll
        for (int r = 0; r < 4; ++r) {
            float p = acc[tt][r] * iS[r];
            if (p > 1e-12f)
                atomicAdd(&avg_acc[256 * q + 16 * tt + ln], p);
        }
    __syncthreads();

    // ---- near-tie slow path (wave 0): numpy fp32-pipeline replica ----
    if (w == 0) {
        for (int row = 0; row < 32; ++row) {
            int tc = candn[row];
            if (tc < 2) continue;
            if (tc > MAXCAND) tc = MAXCAND;
            const float* xr = x + (size_t)(r0 + row) * D;
            *(float4*)&xbuf[ln64 * 4] = *(const float4*)(xr + ln64 * 4);
            // same-wave LDS RAW: compiler inserts waitcnt before first use
            float a2f = __fadd_rn(np_sq_block128(xbuf), np_sq_block128(xbuf + 128));
            float bestd = FLT_MAX; int bestk = K;
            for (int c = 0; c < tc; ++c) {
                int k = candk[row][c];
                double s = 0.0;
                #pragma unroll
                for (int dd = 0; dd < 4; ++dd)
                    s += (double)cb[(size_t)k * D + ln64 * 4 + dd] *
                         (double)xbuf[ln64 * 4 + dd];
                #pragma unroll
                for (int off = 32; off > 0; off >>= 1)
                    s += __shfl_xor(s, off);
                float abf = (float)s;
                float dnp = __fsub_rn(__fadd_rn(a2f, b2[k]), __fmul_rn(2.0f, abf));
                if (dnp < bestd || (dnp == bestd && k < bestk)) {
                    bestd = dnp; bestk = k;
                }
            }
            if (ln64 == 0) bkl[row] = bestk;
        }
    }
    __syncthreads();

    // ---- outputs: wave w -> rows 4w..4w+3 ----
    float wmse = 0.f;
    #pragma unroll
    for (int rr = 0; rr < 4; ++rr) {
        int rl  = 4 * w + rr;
        int row = r0 + rl;
        int bk2 = bkl[rl];
        float4 xv = *(const float4*)(x  + (size_t)row * D + ln64 * 4);
        float4 qv = *(const float4*)(cb + (size_t)bk2 * D + ln64 * 4);
        float dx = qv.x - xv.x, dy = qv.y - xv.y, dz = qv.z - xv.z, dw = qv.w - xv.w;
        float4 st;
        st.x = xv.x + dx; st.y = xv.y + dy; st.z = xv.z + dz; st.w = xv.w + dw;
        *(float4*)(out + (size_t)row * D + ln64 * 4) = st;
        if (ln64 == 0) out[IDX_OFF + row] = (float)bk2;
        wmse += dx * dx + dy * dy + dz * dz + dw * dw;
    }
    #pragma unroll
    for (int off = 32; off > 0; off >>= 1)
        wmse += __shfl_xor(wmse, off);
    if (ln64 == 0) atomicAdd(&scal[0], wmse);
}

// ---- finalize loss ----------------------------------------------------------
__global__ __launch_bounds__(1024)
void vq_fin(const float* __restrict__ avg_acc, const float* __restrict__ scal,
            float* __restrict__ out)
{
    __shared__ float sred[16];
    int t = threadIdx.x;
    float ap = avg_acc[t] * (1.f / 32768.f);
    float v = ap * logf(ap + 1e-5f);
    #pragma unroll
    for (int off = 32; off > 0; off >>= 1) v += __shfl_xor(v, off);
    if ((t & 63) == 0) sred[t >> 6] = v;
    __syncthreads();
    if (t == 0) {
        float s = 0.f;
        for (int w = 0; w < 16; ++w) s += sred[w];
        float avg_entropy = -s;
        float sampleH = -scal[1] * (1.f / 32768.f);
        float mse = scal[0] * (1.f / 8388608.f);
        float loss = 1.25f * mse + 0.1f * (sampleH - avg_entropy);
        out[LOSS_OFF] = loss;
    }
}

extern "C" void kernel_launch(void* const* d_in, const int* in_sizes, int n_in,
                              void* d_out, int out_size, void* d_ws, size_t ws_size,
                              hipStream_t stream)
{
    const float* x  = (const float*)d_in[0];
    const float* cb = (const float*)d_in[1];
    float* out = (float*)d_out;
    float* ws  = (float*)d_ws;
    float*     b2      = ws;                                   // [1024]
    float*     avg_acc = ws + K;                               // [1024]
    float*     scal    = ws + 2 * K;                           // [2]
    _Float16*  c16     = (_Float16*)((char*)d_ws + 16384);     // [1024*256]

    hipMemsetAsync(d_ws, 0, (2 * K + 2) * sizeof(float), stream);
    vq_b2 <<<K / 256, 256, 0, stream>>>(cb, b2);
    vq_cvt<<<(K * D / 4) / 256, 256, 0, stream>>>(cb, c16);
    vq_mfma<<<NROWS / 32, 512, 0, stream>>>(x, cb, c16, b2, avg_acc, scal, out);
    vq_fin<<<1, 1024, 0, stream>>>(avg_acc, scal, out);
}